// Round 10
// baseline (711.411 us; speedup 1.0000x reference)
//
#include <hip/hip_runtime.h>
#include <hip/hip_bf16.h>

// GRU scan with sparse resets. T=1024, B=256, D=128, H=128.
// Round 10: Phase 1: gi = seq @ Wi (f16 -> d_ws, pre-scaled 1/ln2 (r,z),
// 2/ln2 (n), bh_r/bh_z folded in). Phase 2: BPB=2 MFMA scan: 128 blocks x
// 512 thr (8 waves): waves 0-3 -> batch A, waves 4-7 -> batch B (2 indep
// chains per SIMD to fill latency bubbles). h replicated across A rows ->
// MFMA does the k-reduction. q-split tail: lane owns ONE column
// (cg = q>>1), role q&1: 0 -> ht writeback, 1 -> ys store. MFMA depth 2+2
// per gate (shorter dep chain). rst in LDS. BARL (lgkmcnt-only) barrier.
// gi prefetched 4 steps. Fallback if ws too small.

#define T_STEPS 1024
#define B_SZ 256
#define D_SZ 128
#define H_SZ 128

#define SC_RZ 1.44269504f   // 1/ln2
#define SC_N  2.88539008f   // 2/ln2

typedef _Float16 h2 __attribute__((ext_vector_type(2)));
typedef _Float16 h8 __attribute__((ext_vector_type(8)));
typedef _Float16 f16x8 __attribute__((ext_vector_type(8)));
typedef float f32x4 __attribute__((ext_vector_type(4)));

union U8 { h8 v; h2 p[4]; };

__device__ __forceinline__ float dot2f(h2 a, h2 b, float c) {
#if __has_builtin(__builtin_amdgcn_fdot2)
  return __builtin_amdgcn_fdot2(a, b, c, false);
#else
  return c + (float)a.x * (float)b.x + (float)a.y * (float)b.y;
#endif
}

__device__ __forceinline__ float fastrcp(float x) {
#if __has_builtin(__builtin_amdgcn_rcpf)
  return __builtin_amdgcn_rcpf(x);
#else
  return 1.0f / x;
#endif
}

__device__ __forceinline__ float fexp2(float x) {
#if __has_builtin(__builtin_amdgcn_exp2f)
  return __builtin_amdgcn_exp2f(x);
#else
  return __builtin_exp2f(x);
#endif
}

// LDS-only barrier: don't drain vmcnt (ys stores / gi prefetch keep flowing)
#define BARL() asm volatile("s_waitcnt lgkmcnt(0)\n\ts_barrier" ::: "memory")

// ---- phase 1: gi[(t*B+b)*384] (f16) = scale*(seq @ Wi) + scaled bias(r,z) --
__global__ __launch_bounds__(256, 2)
void gi_gemm(const float* __restrict__ seq, const float* __restrict__ Wi,
             const float* __restrict__ bh, _Float16* __restrict__ gi) {
  const int tid = threadIdx.x;
  const int w = tid >> 6, lane = tid & 63;
  const int q = lane >> 4, s = lane & 15;

  f16x8 wF[6][4];
  float bcol[6];
#pragma unroll
  for (int j = 0; j < 6; j++) {
    const int col = w * 96 + j * 16 + s;
    const bool is_n = (w * 96 + j * 16) >= 256;
    const float sc = is_n ? SC_N : SC_RZ;
    bcol[j] = is_n ? 0.f : SC_RZ * bh[col];   // bh_n stays in the scan C-init
#pragma unroll
    for (int kk = 0; kk < 4; kk++) {
      f16x8 f;
#pragma unroll
      for (int e = 0; e < 8; e++)
        f[e] = (_Float16)(sc * Wi[(size_t)(kk * 32 + q * 8 + e) * 384 + col]);
      wF[j][kk] = f;
    }
  }

  __shared__ __align__(16) _Float16 gis[16 * 384];
  const int NROWTILES = (T_STEPS * B_SZ) / 16;

  for (int r = blockIdx.x; r < NROWTILES; r += gridDim.x) {
    const float* xr = &seq[((size_t)r * 16 + s) * D_SZ];
    f16x8 af[4];
#pragma unroll
    for (int kk = 0; kk < 4; kk++) {
      float4 u0 = *(const float4*)(xr + kk * 32 + q * 8);
      float4 u1 = *(const float4*)(xr + kk * 32 + q * 8 + 4);
      f16x8 f;
      f[0] = (_Float16)u0.x; f[1] = (_Float16)u0.y;
      f[2] = (_Float16)u0.z; f[3] = (_Float16)u0.w;
      f[4] = (_Float16)u1.x; f[5] = (_Float16)u1.y;
      f[6] = (_Float16)u1.z; f[7] = (_Float16)u1.w;
      af[kk] = f;
    }
    f32x4 acc[6];
#pragma unroll
    for (int j = 0; j < 6; j++) acc[j] = (f32x4){0.f, 0.f, 0.f, 0.f};
#pragma unroll
    for (int kk = 0; kk < 4; kk++)
#pragma unroll
      for (int j = 0; j < 6; j++)
        acc[j] = __builtin_amdgcn_mfma_f32_16x16x32_f16(af[kk], wF[j][kk],
                                                        acc[j], 0, 0, 0);
#pragma unroll
    for (int j = 0; j < 6; j++) {
      const int col = w * 96 + j * 16 + s;
#pragma unroll
      for (int e = 0; e < 4; e++)
        gis[(q * 4 + e) * 384 + col] = (_Float16)(acc[j][e] + bcol[j]);
    }
    __syncthreads();
    const size_t base = (size_t)r * 16 * 384;
#pragma unroll
    for (int i = 0; i < 3; i++) {
      const int idx = tid + i * 256;
      *(float4*)(gi + base + (size_t)idx * 8) = *(const float4*)(gis + idx * 8);
    }
    __syncthreads();
  }
}

// ---------------- phase 2: BPB=2 MFMA scan, q-split tail -------------------
struct Gi7 { _Float16 r, z, n; };   // gi values for THIS lane's column cq

#define GIL7(T_, G_) { \
    int tl_ = (T_); if (tl_ > T_STEPS - 1) tl_ = T_STEPS - 1; \
    const _Float16* gp_ = gib + (size_t)tl_ * (B_SZ * 384); \
    G_.r = gp_[0]; G_.z = gp_[128]; G_.n = gp_[256]; }

#define STEP7(T_, G_) { \
    const int p_ = (T_) & 1; \
    const int rn_ = rst[bi][((T_) + 1) & (T_STEPS - 1)]; \
    f16x8 hf_[4]; \
    _Pragma("unroll") for (int kk_ = 0; kk_ < 4; kk_++) \
      hf_[kk_] = *(const f16x8*)&ht[p_][bi][kk_ * 32 + q * 8]; \
    const float gr_ = (float)G_.r, gz_ = (float)G_.z, gn_ = (float)G_.n; \
    GIL7((T_) + 4, G_) \
    f32x4 aRa_[2], aRb_[2], aZa_[2], aZb_[2], aNa_[2], aNb_[2]; \
    _Pragma("unroll") for (int c_ = 0; c_ < 2; c_++) { \
      aRa_[c_] = (f32x4){gr_, 0.f, 0.f, 0.f}; \
      aZa_[c_] = (f32x4){gz_, 0.f, 0.f, 0.f}; \
      aNa_[c_] = (f32x4){bh_n, 0.f, 0.f, 0.f}; \
      aRb_[c_] = (f32x4){0.f, 0.f, 0.f, 0.f}; \
      aZb_[c_] = (f32x4){0.f, 0.f, 0.f, 0.f}; \
      aNb_[c_] = (f32x4){0.f, 0.f, 0.f, 0.f}; } \
    _Pragma("unroll") for (int c_ = 0; c_ < 2; c_++) { \
      aRa_[c_] = __builtin_amdgcn_mfma_f32_16x16x32_f16(hf_[0], whF[0][c_][0], aRa_[c_], 0, 0, 0); \
      aZa_[c_] = __builtin_amdgcn_mfma_f32_16x16x32_f16(hf_[0], whF[1][c_][0], aZa_[c_], 0, 0, 0); \
      aNa_[c_] = __builtin_amdgcn_mfma_f32_16x16x32_f16(hf_[0], whF[2][c_][0], aNa_[c_], 0, 0, 0); \
      aRb_[c_] = __builtin_amdgcn_mfma_f32_16x16x32_f16(hf_[2], whF[0][c_][2], aRb_[c_], 0, 0, 0); \
      aZb_[c_] = __builtin_amdgcn_mfma_f32_16x16x32_f16(hf_[2], whF[1][c_][2], aZb_[c_], 0, 0, 0); \
      aNb_[c_] = __builtin_amdgcn_mfma_f32_16x16x32_f16(hf_[2], whF[2][c_][2], aNb_[c_], 0, 0, 0); \
      aRa_[c_] = __builtin_amdgcn_mfma_f32_16x16x32_f16(hf_[1], whF[0][c_][1], aRa_[c_], 0, 0, 0); \
      aZa_[c_] = __builtin_amdgcn_mfma_f32_16x16x32_f16(hf_[1], whF[1][c_][1], aZa_[c_], 0, 0, 0); \
      aNa_[c_] = __builtin_amdgcn_mfma_f32_16x16x32_f16(hf_[1], whF[2][c_][1], aNa_[c_], 0, 0, 0); \
      aRb_[c_] = __builtin_amdgcn_mfma_f32_16x16x32_f16(hf_[3], whF[0][c_][3], aRb_[c_], 0, 0, 0); \
      aZb_[c_] = __builtin_amdgcn_mfma_f32_16x16x32_f16(hf_[3], whF[1][c_][3], aZb_[c_], 0, 0, 0); \
      aNb_[c_] = __builtin_amdgcn_mfma_f32_16x16x32_f16(hf_[3], whF[2][c_][3], aNb_[c_], 0, 0, 0); } \
    const float sR_ = cg ? (aRa_[1][0] + aRb_[1][0]) : (aRa_[0][0] + aRb_[0][0]); \
    const float sZ_ = cg ? (aZa_[1][0] + aZb_[1][0]) : (aZa_[0][0] + aZb_[0][0]); \
    const float sN_ = cg ? (aNa_[1][0] + aNb_[1][0]) : (aNa_[0][0] + aNb_[0][0]); \
    const float r_ = fastrcp(1.f + fexp2(-sR_)); \
    const float z_ = fastrcp(1.f + fexp2(-sZ_)); \
    const float e2_ = fexp2(gn_ + r_ * sN_); \
    const float n_ = 1.f - 2.f * fastrcp(e2_ + 1.f); \
    const float hnew_ = n_ + z_ * (hu - n_); \
    hu = rn_ ? h0c : hnew_; \
    if (wrH) ht[p_ ^ 1][bi][cq] = (_Float16)hu; \
    else ys[((size_t)(T_) * B_SZ + b) * H_SZ + cq] = hnew_; \
    if ((T_) == T_STEPS - 1 && wrH) out[(size_t)b * H_SZ + cq] = hnew_; \
    BARL(); }

__global__ __launch_bounds__(512, 2)
void gru_scan7(const _Float16* __restrict__ gi,
               const int* __restrict__ resets,
               const float* __restrict__ h0,
               const float* __restrict__ Wh,
               const float* __restrict__ bh,
               float* __restrict__ out) {
  const int tid = threadIdx.x;
  const int w = tid >> 6;
  const int bi = w >> 2;                 // batch within block (0/1)
  const int wl = w & 3;                  // col-group wave 0..3
  const int b = blockIdx.x * 2 + bi;
  const int lane = tid & 63;
  const int q = lane >> 4;               // A k-group
  const int s = lane & 15;               // B/C col within tile
  const int c0 = wl * 32 + s;
  const int cg = q >> 1;                 // which 16-col tile this lane owns
  const int cq = c0 + (cg << 4);         // this lane's column
  const bool wrH = ((q & 1) == 0);       // role: h-writeback vs ys store

  __shared__ int rst[2][T_STEPS];                      // 8 KB
  __shared__ __align__(16) _Float16 ht[2][2][H_SZ];    // 1 KB

  for (int i = tid; i < 2 * T_STEPS; i += 512) {
    const int bi_ = i >> 10, t_ = i & (T_STEPS - 1);
    rst[bi_][t_] = resets[(size_t)t_ * B_SZ + blockIdx.x * 2 + bi_];
  }

  // Wh B-frags (pre-scaled): gate g3, coltile c2 -> col g3*128+wl*32+c2*16+s
  f16x8 whF[3][2][4];
#pragma unroll
  for (int g3 = 0; g3 < 3; g3++) {
    const float sc = (g3 == 2) ? SC_N : SC_RZ;
#pragma unroll
    for (int c2 = 0; c2 < 2; c2++) {
      const int col = g3 * H_SZ + wl * 32 + c2 * 16 + s;
#pragma unroll
      for (int kk = 0; kk < 4; kk++) {
        f16x8 f;
#pragma unroll
        for (int e = 0; e < 8; e++)
          f[e] = (_Float16)(sc * Wh[(size_t)(kk * 32 + q * 8 + e) * 384 + col]);
        whF[g3][c2][kk] = f;
      }
    }
  }

  const float bh_n = SC_N * bh[2 * H_SZ + cq];
  const float h0c = h0[(size_t)b * H_SZ + cq];
  float hu = h0c;

  if (tid < 2 * H_SZ)
    ht[0][tid >> 7][tid & 127] =
        (_Float16)h0[(size_t)(blockIdx.x * 2 + (tid >> 7)) * H_SZ + (tid & 127)];

  const _Float16* gib = gi + (size_t)b * 384 + cq;
  Gi7 gA, gB, gC, gD;
  GIL7(0, gA)
  GIL7(1, gB)
  GIL7(2, gC)
  GIL7(3, gD)
  __syncthreads();

  float* ys = out + (size_t)B_SZ * H_SZ;  // out = [final_carry] ++ [ys]

#pragma unroll 1
  for (int t = 0; t < T_STEPS; t += 8) {
    STEP7(t + 0, gA)
    STEP7(t + 1, gB)
    STEP7(t + 2, gC)
    STEP7(t + 3, gD)
    STEP7(t + 4, gA)
    STEP7(t + 5, gB)
    STEP7(t + 6, gC)
    STEP7(t + 7, gD)
  }
}

// ---------------- fallback: fused single-kernel (ws too small) ------------
__global__ __launch_bounds__(512, 2)
void gru_scan_fb(const float* __restrict__ seq,
                 const int* __restrict__ resets,
                 const float* __restrict__ h0,
                 const float* __restrict__ Wi,
                 const float* __restrict__ Wh,
                 const float* __restrict__ bh,
                 float* __restrict__ out) {
  const int b = blockIdx.x;
  const int tid = threadIdx.x;
  const int w = tid >> 6;
  const int lane = tid & 63;
  const int c = (w << 4) | (lane & 15);
  const int g = lane >> 4;

  __shared__ int rst[T_STEPS];
  __shared__ __align__(16) _Float16 x16[2][D_SZ];
  __shared__ __align__(16) _Float16 hh16[2][H_SZ];

  for (int i = tid; i < T_STEPS; i += 512) rst[i] = resets[(size_t)i * B_SZ + b];

  h2 wiR[3][16], whR[3][16];
  const int k0 = g * 32;
#pragma unroll
  for (int ch = 0; ch < 3; ch++) {
    const int col = ch * H_SZ + c;
#pragma unroll
    for (int j = 0; j < 16; j++) {
      const int k = k0 + 2 * j;
      h2 wa; wa.x = (_Float16)Wi[(size_t)k * 384 + col];
             wa.y = (_Float16)Wi[(size_t)(k + 1) * 384 + col];
      wiR[ch][j] = wa;
      h2 wb; wb.x = (_Float16)Wh[(size_t)k * 384 + col];
             wb.y = (_Float16)Wh[(size_t)(k + 1) * 384 + col];
      whR[ch][j] = wb;
    }
  }

  const float bhr = bh[c], bhz = bh[H_SZ + c], bhn = bh[2 * H_SZ + c];
  const float h0c = h0[(size_t)b * H_SZ + c];
  float hu = h0c;

  if (tid < H_SZ) {
    hh16[0][tid] = (_Float16)h0[(size_t)b * H_SZ + tid];
    x16[0][tid]  = (_Float16)seq[((size_t)0 * B_SZ + b) * D_SZ + tid];
  }
  float xA = 0.f, xB = 0.f;
  if (tid < D_SZ) {
    xA = seq[((size_t)1 * B_SZ + b) * D_SZ + tid];
    xB = seq[((size_t)2 * B_SZ + b) * D_SZ + tid];
  }
  __syncthreads();

  float* ys = out + (size_t)B_SZ * H_SZ;

#pragma unroll 1
  for (int t = 0; t < T_STEPS; t++) {
    const int p = t & 1;
    const int rnext = rst[(t + 1) & (T_STEPS - 1)];

    const h8* xb = (const h8*)&x16[p][g * 32];
    const h8* hb = (const h8*)&hh16[p][g * 32];
    float cr = 0.f, cz = 0.f, ci = 0.f, chn = 0.f;
#pragma unroll
    for (int qq = 0; qq < 4; qq++) {
      U8 ux, uh; ux.v = xb[qq]; uh.v = hb[qq];
#pragma unroll
      for (int j = 0; j < 4; j++) {
        const int idx = qq * 4 + j;
        cr  = dot2f(ux.p[j], wiR[0][idx], cr);
        cz  = dot2f(ux.p[j], wiR[1][idx], cz);
        ci  = dot2f(ux.p[j], wiR[2][idx], ci);
        cr  = dot2f(uh.p[j], whR[0][idx], cr);
        cz  = dot2f(uh.p[j], whR[1][idx], cz);
        chn = dot2f(uh.p[j], whR[2][idx], chn);
      }
    }
    cr  += __shfl_xor(cr, 16, 64);
    cz  += __shfl_xor(cz, 16, 64);
    ci  += __shfl_xor(ci, 16, 64);
    chn += __shfl_xor(chn, 16, 64);
    cr  += __shfl_xor(cr, 32, 64);
    cz  += __shfl_xor(cz, 32, 64);
    ci  += __shfl_xor(ci, 32, 64);
    chn += __shfl_xor(chn, 32, 64);

    const float ar = cr + bhr;
    const float az = cz + bhz;
    const float ah = chn + bhn;
    const float r = fastrcp(1.f + __expf(-ar));
    const float z = fastrcp(1.f + __expf(-az));
    const float ta = ci + r * ah;
    const float e2 = __expf(2.f * ta);
    const float n = 1.f - 2.f * fastrcp(e2 + 1.f);
    const float hnew = n + z * (hu - n);
    const float hunew = rnext ? h0c : hnew;
    hu = hunew;

    if (g == 0) {
      ys[((size_t)t * B_SZ + b) * H_SZ + c] = hnew;
      hh16[p ^ 1][c] = (_Float16)hunew;
      if (t == T_STEPS - 1) out[(size_t)b * H_SZ + c] = hnew;
    }
    if (tid < D_SZ) {
      x16[p ^ 1][tid] = (_Float16)xA;
      xA = xB;
      int tt = t + 3; if (tt > T_STEPS - 1) tt = T_STEPS - 1;
      xB = seq[((size_t)tt * B_SZ + b) * D_SZ + tid];
    }
    __syncthreads();
  }
}

extern "C" void kernel_launch(void* const* d_in, const int* in_sizes, int n_in,
                              void* d_out, int out_size, void* d_ws, size_t ws_size,
                              hipStream_t stream) {
  const float* seq    = (const float*)d_in[0];
  const int*   resets = (const int*)d_in[1];
  const float* h0     = (const float*)d_in[2];
  const float* Wi     = (const float*)d_in[3];
  const float* Wh     = (const float*)d_in[4];
  const float* bh     = (const float*)d_in[5];
  (void)in_sizes; (void)n_in; (void)out_size;

  const size_t need = (size_t)T_STEPS * B_SZ * 384 * sizeof(_Float16);
  if (ws_size >= need && d_ws != nullptr) {
    _Float16* gi = (_Float16*)d_ws;
    gi_gemm<<<1024, 256, 0, stream>>>(seq, Wi, bh, gi);
    gru_scan7<<<B_SZ / 2, 512, 0, stream>>>(gi, resets, h0, Wh, bh,
                                            (float*)d_out);
  } else {
    gru_scan_fb<<<B_SZ, 512, 0, stream>>>(seq, resets, h0, Wi, Wh, bh,
                                          (float*)d_out);
  }
}

// Round 11
// 508.902 us; speedup vs baseline: 1.3979x; 1.3979x over previous
//
#include <hip/hip_runtime.h>
#include <hip/hip_bf16.h>

// GRU scan with sparse resets. T=1024, B=256, D=128, H=128.
// Round 11: Phase 1: gi = seq @ Wi (f16 -> d_ws, pre-scaled 1/ln2 (r,z),
// 2/ln2 (n); bh_r/bh_z folded). Phase 2: BPB=1 MFMA scan (scan5 structure,
// step-chain polished): 256 blocks x 256 thr (4 waves, 1/SIMD).
// - zero-C MFMA inits (persistent zero4; gi added in tail) - no acc movs
// - q-split tail: cg=q>>1 picks ONE column chain per lane; writes by q&1
//   (ht writeback vs ys store); final carry stored after the loop
// - MFMA order: r/z (16) then n (8) so sigma(r),sigma(z) hide n-issue
// - rst in LDS, read at step top (off-chain). BARL lgkmcnt-only barrier.
// gi prefetched 4 steps. Fallback if ws too small.

#define T_STEPS 1024
#define B_SZ 256
#define D_SZ 128
#define H_SZ 128

#define SC_RZ 1.44269504f   // 1/ln2
#define SC_N  2.88539008f   // 2/ln2

typedef _Float16 h2 __attribute__((ext_vector_type(2)));
typedef _Float16 h8 __attribute__((ext_vector_type(8)));
typedef _Float16 f16x8 __attribute__((ext_vector_type(8)));
typedef float f32x4 __attribute__((ext_vector_type(4)));

union U8 { h8 v; h2 p[4]; };

__device__ __forceinline__ float dot2f(h2 a, h2 b, float c) {
#if __has_builtin(__builtin_amdgcn_fdot2)
  return __builtin_amdgcn_fdot2(a, b, c, false);
#else
  return c + (float)a.x * (float)b.x + (float)a.y * (float)b.y;
#endif
}

__device__ __forceinline__ float fastrcp(float x) {
#if __has_builtin(__builtin_amdgcn_rcpf)
  return __builtin_amdgcn_rcpf(x);
#else
  return 1.0f / x;
#endif
}

__device__ __forceinline__ float fexp2(float x) {
#if __has_builtin(__builtin_amdgcn_exp2f)
  return __builtin_amdgcn_exp2f(x);
#else
  return __builtin_exp2f(x);
#endif
}

// LDS-only barrier: don't drain vmcnt (ys stores / gi prefetch keep flowing)
#define BARL() asm volatile("s_waitcnt lgkmcnt(0)\n\ts_barrier" ::: "memory")

// ---- phase 1: gi[(t*B+b)*384] (f16) = scale*(seq @ Wi) + scaled bias(r,z) --
__global__ __launch_bounds__(256, 2)
void gi_gemm(const float* __restrict__ seq, const float* __restrict__ Wi,
             const float* __restrict__ bh, _Float16* __restrict__ gi) {
  const int tid = threadIdx.x;
  const int w = tid >> 6, lane = tid & 63;
  const int q = lane >> 4, s = lane & 15;

  f16x8 wF[6][4];
  float bcol[6];
#pragma unroll
  for (int j = 0; j < 6; j++) {
    const int col = w * 96 + j * 16 + s;
    const bool is_n = (w * 96 + j * 16) >= 256;
    const float sc = is_n ? SC_N : SC_RZ;
    bcol[j] = is_n ? 0.f : SC_RZ * bh[col];   // bh_n stays in the scan tail
#pragma unroll
    for (int kk = 0; kk < 4; kk++) {
      f16x8 f;
#pragma unroll
      for (int e = 0; e < 8; e++)
        f[e] = (_Float16)(sc * Wi[(size_t)(kk * 32 + q * 8 + e) * 384 + col]);
      wF[j][kk] = f;
    }
  }

  __shared__ __align__(16) _Float16 gis[16 * 384];
  const int NROWTILES = (T_STEPS * B_SZ) / 16;

  for (int r = blockIdx.x; r < NROWTILES; r += gridDim.x) {
    const float* xr = &seq[((size_t)r * 16 + s) * D_SZ];
    f16x8 af[4];
#pragma unroll
    for (int kk = 0; kk < 4; kk++) {
      float4 u0 = *(const float4*)(xr + kk * 32 + q * 8);
      float4 u1 = *(const float4*)(xr + kk * 32 + q * 8 + 4);
      f16x8 f;
      f[0] = (_Float16)u0.x; f[1] = (_Float16)u0.y;
      f[2] = (_Float16)u0.z; f[3] = (_Float16)u0.w;
      f[4] = (_Float16)u1.x; f[5] = (_Float16)u1.y;
      f[6] = (_Float16)u1.z; f[7] = (_Float16)u1.w;
      af[kk] = f;
    }
    f32x4 acc[6];
#pragma unroll
    for (int j = 0; j < 6; j++) acc[j] = (f32x4){0.f, 0.f, 0.f, 0.f};
#pragma unroll
    for (int kk = 0; kk < 4; kk++)
#pragma unroll
      for (int j = 0; j < 6; j++)
        acc[j] = __builtin_amdgcn_mfma_f32_16x16x32_f16(af[kk], wF[j][kk],
                                                        acc[j], 0, 0, 0);
#pragma unroll
    for (int j = 0; j < 6; j++) {
      const int col = w * 96 + j * 16 + s;
#pragma unroll
      for (int e = 0; e < 4; e++)
        gis[(q * 4 + e) * 384 + col] = (_Float16)(acc[j][e] + bcol[j]);
    }
    __syncthreads();
    const size_t base = (size_t)r * 16 * 384;
#pragma unroll
    for (int i = 0; i < 3; i++) {
      const int idx = tid + i * 256;
      *(float4*)(gi + base + (size_t)idx * 8) = *(const float4*)(gis + idx * 8);
    }
    __syncthreads();
  }
}

// ---------------- phase 2: BPB=1 MFMA scan, polished chain -----------------
struct Gi8 { _Float16 r, z, n; };   // gi values for THIS lane's column cq

#define GIL8(T_, G_) { \
    int tl_ = (T_); if (tl_ > T_STEPS - 1) tl_ = T_STEPS - 1; \
    const _Float16* gp_ = gib + (size_t)tl_ * (B_SZ * 384); \
    G_.r = gp_[0]; G_.z = gp_[128]; G_.n = gp_[256]; }

#define STEP8(T_, G_) { \
    const int p_ = (T_) & 1; \
    const int rn_ = rst[((T_) + 1) & (T_STEPS - 1)]; \
    f16x8 hf0_ = *(const f16x8*)&ht[p_][ 0 + q * 8]; \
    f16x8 hf1_ = *(const f16x8*)&ht[p_][32 + q * 8]; \
    f16x8 hf2_ = *(const f16x8*)&ht[p_][64 + q * 8]; \
    f16x8 hf3_ = *(const f16x8*)&ht[p_][96 + q * 8]; \
    const float gr_ = (float)G_.r, gz_ = (float)G_.z, gn_ = (float)G_.n; \
    GIL8((T_) + 4, G_) \
    /* r,z MFMAs first (zero-C inits) */ \
    f32x4 aR0_ = __builtin_amdgcn_mfma_f32_16x16x32_f16(hf0_, whF[0][0][0], Z4, 0, 0, 0); \
    f32x4 aR1_ = __builtin_amdgcn_mfma_f32_16x16x32_f16(hf0_, whF[0][1][0], Z4, 0, 0, 0); \
    f32x4 aZ0_ = __builtin_amdgcn_mfma_f32_16x16x32_f16(hf0_, whF[1][0][0], Z4, 0, 0, 0); \
    f32x4 aZ1_ = __builtin_amdgcn_mfma_f32_16x16x32_f16(hf0_, whF[1][1][0], Z4, 0, 0, 0); \
    aR0_ = __builtin_amdgcn_mfma_f32_16x16x32_f16(hf1_, whF[0][0][1], aR0_, 0, 0, 0); \
    aR1_ = __builtin_amdgcn_mfma_f32_16x16x32_f16(hf1_, whF[0][1][1], aR1_, 0, 0, 0); \
    aZ0_ = __builtin_amdgcn_mfma_f32_16x16x32_f16(hf1_, whF[1][0][1], aZ0_, 0, 0, 0); \
    aZ1_ = __builtin_amdgcn_mfma_f32_16x16x32_f16(hf1_, whF[1][1][1], aZ1_, 0, 0, 0); \
    aR0_ = __builtin_amdgcn_mfma_f32_16x16x32_f16(hf2_, whF[0][0][2], aR0_, 0, 0, 0); \
    aR1_ = __builtin_amdgcn_mfma_f32_16x16x32_f16(hf2_, whF[0][1][2], aR1_, 0, 0, 0); \
    aZ0_ = __builtin_amdgcn_mfma_f32_16x16x32_f16(hf2_, whF[1][0][2], aZ0_, 0, 0, 0); \
    aZ1_ = __builtin_amdgcn_mfma_f32_16x16x32_f16(hf2_, whF[1][1][2], aZ1_, 0, 0, 0); \
    aR0_ = __builtin_amdgcn_mfma_f32_16x16x32_f16(hf3_, whF[0][0][3], aR0_, 0, 0, 0); \
    aR1_ = __builtin_amdgcn_mfma_f32_16x16x32_f16(hf3_, whF[0][1][3], aR1_, 0, 0, 0); \
    aZ0_ = __builtin_amdgcn_mfma_f32_16x16x32_f16(hf3_, whF[1][0][3], aZ0_, 0, 0, 0); \
    aZ1_ = __builtin_amdgcn_mfma_f32_16x16x32_f16(hf3_, whF[1][1][3], aZ1_, 0, 0, 0); \
    /* n MFMAs; sigma(r),sigma(z) scheduled under their issue */ \
    f32x4 aN0_ = __builtin_amdgcn_mfma_f32_16x16x32_f16(hf0_, whF[2][0][0], Z4, 0, 0, 0); \
    f32x4 aN1_ = __builtin_amdgcn_mfma_f32_16x16x32_f16(hf0_, whF[2][1][0], Z4, 0, 0, 0); \
    aN0_ = __builtin_amdgcn_mfma_f32_16x16x32_f16(hf1_, whF[2][0][1], aN0_, 0, 0, 0); \
    aN1_ = __builtin_amdgcn_mfma_f32_16x16x32_f16(hf1_, whF[2][1][1], aN1_, 0, 0, 0); \
    aN0_ = __builtin_amdgcn_mfma_f32_16x16x32_f16(hf2_, whF[2][0][2], aN0_, 0, 0, 0); \
    aN1_ = __builtin_amdgcn_mfma_f32_16x16x32_f16(hf2_, whF[2][1][2], aN1_, 0, 0, 0); \
    aN0_ = __builtin_amdgcn_mfma_f32_16x16x32_f16(hf3_, whF[2][0][3], aN0_, 0, 0, 0); \
    aN1_ = __builtin_amdgcn_mfma_f32_16x16x32_f16(hf3_, whF[2][1][3], aN1_, 0, 0, 0); \
    const float sR_ = (cg ? aR1_[0] : aR0_[0]) + gr_; \
    const float sZ_ = (cg ? aZ1_[0] : aZ0_[0]) + gz_; \
    const float r_ = fastrcp(1.f + fexp2(-sR_)); \
    const float z_ = fastrcp(1.f + fexp2(-sZ_)); \
    const float sN_ = (cg ? aN1_[0] : aN0_[0]) + bh_n; \
    const float e2_ = fexp2(gn_ + r_ * sN_); \
    const float n_ = 1.f - 2.f * fastrcp(e2_ + 1.f); \
    const float hnew_ = n_ + z_ * (hu - n_); \
    hu = rn_ ? h0c : hnew_; \
    yfin = hnew_; \
    if (wrH) ht[p_ ^ 1][cq] = (_Float16)hu; \
    else ys[((size_t)(T_) * B_SZ + b) * H_SZ + cq] = hnew_; \
    BARL(); }

__global__ __launch_bounds__(256, 1)
void gru_scan8(const _Float16* __restrict__ gi,
               const int* __restrict__ resets,
               const float* __restrict__ h0,
               const float* __restrict__ Wh,
               const float* __restrict__ bh,
               float* __restrict__ out) {
  const int b = blockIdx.x;
  const int tid = threadIdx.x;
  const int w = tid >> 6;          // wave 0..3: cols [w*32, w*32+32)
  const int lane = tid & 63;
  const int q = lane >> 4;         // A k-group / role group
  const int s = lane & 15;         // B/C col within tile
  const int cg = q >> 1;           // which 16-col tile this lane owns
  const int cq = w * 32 + (cg << 4) + s;  // this lane's column
  const bool wrH = ((q & 1) == 0); // role: h-writeback vs ys store

  __shared__ int rst[T_STEPS];                      // 4 KB
  __shared__ __align__(16) _Float16 ht[2][H_SZ];    // 512 B, linear

  for (int i = tid; i < T_STEPS; i += 256)
    rst[i] = resets[(size_t)i * B_SZ + b];

  // Wh B-frags (pre-scaled): gate g3, coltile c2 -> col g3*128 + w*32 +
  // c2*16 + s; k = kk*32 + q*8 + e.
  f16x8 whF[3][2][4];
#pragma unroll
  for (int g3 = 0; g3 < 3; g3++) {
    const float sc = (g3 == 2) ? SC_N : SC_RZ;
#pragma unroll
    for (int c2 = 0; c2 < 2; c2++) {
      const int col = g3 * H_SZ + w * 32 + c2 * 16 + s;
#pragma unroll
      for (int kk = 0; kk < 4; kk++) {
        f16x8 f;
#pragma unroll
        for (int e = 0; e < 8; e++)
          f[e] = (_Float16)(sc * Wh[(size_t)(kk * 32 + q * 8 + e) * 384 + col]);
        whF[g3][c2][kk] = f;
      }
    }
  }

  const f32x4 Z4 = {0.f, 0.f, 0.f, 0.f};
  const float bh_n = SC_N * bh[2 * H_SZ + cq];
  const float h0c = h0[(size_t)b * H_SZ + cq];
  float hu = h0c;
  float yfin = h0c;

  if (tid < H_SZ) ht[0][tid] = (_Float16)h0[(size_t)b * H_SZ + tid];

  const _Float16* gib = gi + (size_t)b * 384 + cq;
  Gi8 gA, gB, gC, gD;
  GIL8(0, gA)
  GIL8(1, gB)
  GIL8(2, gC)
  GIL8(3, gD)
  __syncthreads();

  float* ys = out + (size_t)B_SZ * H_SZ;  // out = [final_carry] ++ [ys]

#pragma unroll 1
  for (int t = 0; t < T_STEPS; t += 8) {
    STEP8(t + 0, gA)
    STEP8(t + 1, gB)
    STEP8(t + 2, gC)
    STEP8(t + 3, gD)
    STEP8(t + 4, gA)
    STEP8(t + 5, gB)
    STEP8(t + 6, gC)
    STEP8(t + 7, gD)
  }
  if (wrH) out[(size_t)b * H_SZ + cq] = yfin;  // final carry = hnew(1023)
}

// ---------------- fallback: fused single-kernel (ws too small) ------------
__global__ __launch_bounds__(512, 2)
void gru_scan_fb(const float* __restrict__ seq,
                 const int* __restrict__ resets,
                 const float* __restrict__ h0,
                 const float* __restrict__ Wi,
                 const float* __restrict__ Wh,
                 const float* __restrict__ bh,
                 float* __restrict__ out) {
  const int b = blockIdx.x;
  const int tid = threadIdx.x;
  const int w = tid >> 6;
  const int lane = tid & 63;
  const int c = (w << 4) | (lane & 15);
  const int g = lane >> 4;

  __shared__ int rst[T_STEPS];
  __shared__ __align__(16) _Float16 x16[2][D_SZ];
  __shared__ __align__(16) _Float16 hh16[2][H_SZ];

  for (int i = tid; i < T_STEPS; i += 512) rst[i] = resets[(size_t)i * B_SZ + b];

  h2 wiR[3][16], whR[3][16];
  const int k0 = g * 32;
#pragma unroll
  for (int ch = 0; ch < 3; ch++) {
    const int col = ch * H_SZ + c;
#pragma unroll
    for (int j = 0; j < 16; j++) {
      const int k = k0 + 2 * j;
      h2 wa; wa.x = (_Float16)Wi[(size_t)k * 384 + col];
             wa.y = (_Float16)Wi[(size_t)(k + 1) * 384 + col];
      wiR[ch][j] = wa;
      h2 wb; wb.x = (_Float16)Wh[(size_t)k * 384 + col];
             wb.y = (_Float16)Wh[(size_t)(k + 1) * 384 + col];
      whR[ch][j] = wb;
    }
  }

  const float bhr = bh[c], bhz = bh[H_SZ + c], bhn = bh[2 * H_SZ + c];
  const float h0c = h0[(size_t)b * H_SZ + c];
  float hu = h0c;

  if (tid < H_SZ) {
    hh16[0][tid] = (_Float16)h0[(size_t)b * H_SZ + tid];
    x16[0][tid]  = (_Float16)seq[((size_t)0 * B_SZ + b) * D_SZ + tid];
  }
  float xA = 0.f, xB = 0.f;
  if (tid < D_SZ) {
    xA = seq[((size_t)1 * B_SZ + b) * D_SZ + tid];
    xB = seq[((size_t)2 * B_SZ + b) * D_SZ + tid];
  }
  __syncthreads();

  float* ys = out + (size_t)B_SZ * H_SZ;

#pragma unroll 1
  for (int t = 0; t < T_STEPS; t++) {
    const int p = t & 1;
    const int rnext = rst[(t + 1) & (T_STEPS - 1)];

    const h8* xb = (const h8*)&x16[p][g * 32];
    const h8* hb = (const h8*)&hh16[p][g * 32];
    float cr = 0.f, cz = 0.f, ci = 0.f, chn = 0.f;
#pragma unroll
    for (int qq = 0; qq < 4; qq++) {
      U8 ux, uh; ux.v = xb[qq]; uh.v = hb[qq];
#pragma unroll
      for (int j = 0; j < 4; j++) {
        const int idx = qq * 4 + j;
        cr  = dot2f(ux.p[j], wiR[0][idx], cr);
        cz  = dot2f(ux.p[j], wiR[1][idx], cz);
        ci  = dot2f(ux.p[j], wiR[2][idx], ci);
        cr  = dot2f(uh.p[j], whR[0][idx], cr);
        cz  = dot2f(uh.p[j], whR[1][idx], cz);
        chn = dot2f(uh.p[j], whR[2][idx], chn);
      }
    }
    cr  += __shfl_xor(cr, 16, 64);
    cz  += __shfl_xor(cz, 16, 64);
    ci  += __shfl_xor(ci, 16, 64);
    chn += __shfl_xor(chn, 16, 64);
    cr  += __shfl_xor(cr, 32, 64);
    cz  += __shfl_xor(cz, 32, 64);
    ci  += __shfl_xor(ci, 32, 64);
    chn += __shfl_xor(chn, 32, 64);

    const float ar = cr + bhr;
    const float az = cz + bhz;
    const float ah = chn + bhn;
    const float r = fastrcp(1.f + __expf(-ar));
    const float z = fastrcp(1.f + __expf(-az));
    const float ta = ci + r * ah;
    const float e2 = __expf(2.f * ta);
    const float n = 1.f - 2.f * fastrcp(e2 + 1.f);
    const float hnew = n + z * (hu - n);
    const float hunew = rnext ? h0c : hnew;
    hu = hunew;

    if (g == 0) {
      ys[((size_t)t * B_SZ + b) * H_SZ + c] = hnew;
      hh16[p ^ 1][c] = (_Float16)hunew;
      if (t == T_STEPS - 1) out[(size_t)b * H_SZ + c] = hnew;
    }
    if (tid < D_SZ) {
      x16[p ^ 1][tid] = (_Float16)xA;
      xA = xB;
      int tt = t + 3; if (tt > T_STEPS - 1) tt = T_STEPS - 1;
      xB = seq[((size_t)tt * B_SZ + b) * D_SZ + tid];
    }
    __syncthreads();
  }
}

extern "C" void kernel_launch(void* const* d_in, const int* in_sizes, int n_in,
                              void* d_out, int out_size, void* d_ws, size_t ws_size,
                              hipStream_t stream) {
  const float* seq    = (const float*)d_in[0];
  const int*   resets = (const int*)d_in[1];
  const float* h0     = (const float*)d_in[2];
  const float* Wi     = (const float*)d_in[3];
  const float* Wh     = (const float*)d_in[4];
  const float* bh     = (const float*)d_in[5];
  (void)in_sizes; (void)n_in; (void)out_size;

  const size_t need = (size_t)T_STEPS * B_SZ * 384 * sizeof(_Float16);
  if (ws_size >= need && d_ws != nullptr) {
    _Float16* gi = (_Float16*)d_ws;
    gi_gemm<<<1024, 256, 0, stream>>>(seq, Wi, bh, gi);
    gru_scan8<<<B_SZ, 256, 0, stream>>>(gi, resets, h0, Wh, bh, (float*)d_out);
  } else {
    gru_scan_fb<<<B_SZ, 512, 0, stream>>>(seq, resets, h0, Wi, Wh, bh,
                                          (float*)d_out);
  }
}